// Round 1
// baseline (806.006 us; speedup 1.0000x reference)
//
#include <hip/hip_runtime.h>

// Problem constants (also derived from in_sizes at launch)
#define FDIM 128

// ---------------- CSR build ----------------

__global__ void hist_kernel(const int* __restrict__ tgt, int* __restrict__ count, int ne) {
    int e = blockIdx.x * blockDim.x + threadIdx.x;
    if (e < ne) atomicAdd(&count[tgt[e]], 1);
}

__global__ void dis_kernel(const int* __restrict__ count, float* __restrict__ dis, int n) {
    int i = blockIdx.x * blockDim.x + threadIdx.x;
    if (i < n) {
        float d = (float)(count[i] + 1);   // +1 self-loop
        dis[i] = rsqrtf(d);
    }
}

// single-block exclusive scan over n counts -> rowptr[0..n], cursor copy
__global__ void scan_kernel(const int* __restrict__ count, int* __restrict__ rowptr,
                            int* __restrict__ cursor, int n) {
    __shared__ int sums[1024];
    int tid = threadIdx.x;
    int chunk = (n + 1023) / 1024;
    int start = tid * chunk;
    int end   = min(start + chunk, n);
    int s = 0;
    for (int i = start; i < end; i++) s += count[i];
    sums[tid] = s;
    __syncthreads();
    // inclusive Hillis-Steele scan
    for (int off = 1; off < 1024; off <<= 1) {
        int v = sums[tid];
        int u = (tid >= off) ? sums[tid - off] : 0;
        __syncthreads();
        sums[tid] = v + u;
        __syncthreads();
    }
    int run = (tid == 0) ? 0 : sums[tid - 1];   // exclusive prefix for this chunk
    for (int i = start; i < end; i++) {
        rowptr[i] = run;
        cursor[i] = run;
        run += count[i];
    }
    if (tid == 1023) rowptr[n] = run;           // == ne (last chunk is past n, run==total)
}

__global__ void fill_kernel(const int* __restrict__ src, const int* __restrict__ tgt,
                            const float* __restrict__ dis,
                            int* __restrict__ cursor, int* __restrict__ csr_src,
                            float* __restrict__ csr_val, int ne) {
    int e = blockIdx.x * blockDim.x + threadIdx.x;
    if (e < ne) {
        int t = tgt[e];
        int s = src[e];
        int slot = atomicAdd(&cursor[t], 1);
        csr_src[slot] = s;
        csr_val[slot] = dis[s];
    }
}

// ---------------- GEMM: Out[n][128] = A[n][128] @ W[128][128] ----------------
// block 256 threads, tile 128x128, micro-tile 8x8, BK=32

__global__ __launch_bounds__(256) void gemm_kernel(const float* __restrict__ A,
                                                   const float* __restrict__ W,
                                                   float* __restrict__ Out, int n) {
    __shared__ float As[32][128];   // [k][m]  (A tile transposed)
    __shared__ float Bs[32][128];   // [k][j]
    int tid = threadIdx.x;
    int tx = tid & 15;              // col group
    int ty = tid >> 4;              // row group
    int row0 = blockIdx.x * 128;
    float acc[8][8] = {};

    for (int k0 = 0; k0 < 128; k0 += 32) {
        // load A tile: 128 rows x 32 k; thread -> row = tid/2, 16 consecutive floats
        {
            int r  = tid >> 1;
            int c4 = (tid & 1) * 4;
            int grow = row0 + r;
            const float4* ap = (const float4*)(A + (size_t)grow * FDIM + k0);
            #pragma unroll
            for (int i = 0; i < 4; i++) {
                float4 v = (grow < n) ? ap[c4 + i] : make_float4(0.f, 0.f, 0.f, 0.f);
                int kk = (c4 + i) * 4;
                As[kk + 0][r] = v.x;
                As[kk + 1][r] = v.y;
                As[kk + 2][r] = v.z;
                As[kk + 3][r] = v.w;
            }
            // load W tile: 32 k x 128 j (fully coalesced float4)
            #pragma unroll
            for (int i = 0; i < 4; i++) {
                int f  = tid + i * 256;      // float4 index 0..1023
                int kk = f >> 5;
                int j4 = f & 31;
                float4 v = ((const float4*)(W + (size_t)(k0 + kk) * FDIM))[j4];
                *((float4*)&Bs[kk][j4 * 4]) = v;
            }
        }
        __syncthreads();
        #pragma unroll
        for (int k = 0; k < 32; k++) {
            float a[8], b[8];
            *(float4*)&a[0] = *(const float4*)&As[k][ty * 8];
            *(float4*)&a[4] = *(const float4*)&As[k][ty * 8 + 4];
            *(float4*)&b[0] = *(const float4*)&Bs[k][tx * 8];
            *(float4*)&b[4] = *(const float4*)&Bs[k][tx * 8 + 4];
            #pragma unroll
            for (int m = 0; m < 8; m++)
                #pragma unroll
                for (int j = 0; j < 8; j++)
                    acc[m][j] += a[m] * b[j];
        }
        __syncthreads();
    }

    #pragma unroll
    for (int m = 0; m < 8; m++) {
        int r = row0 + ty * 8 + m;
        if (r < n) {
            float4* op = (float4*)(Out + (size_t)r * FDIM + tx * 8);
            op[0] = make_float4(acc[m][0], acc[m][1], acc[m][2], acc[m][3]);
            op[1] = make_float4(acc[m][4], acc[m][5], acc[m][6], acc[m][7]);
        }
    }
}

// ---------------- Aggregation (pull) + bias + relu + pool ----------------
// block 1024 = 16 waves, one wave per node; lane handles 2 features (float2)

__global__ __launch_bounds__(1024) void agg_kernel(const float* __restrict__ hw,
                                                   const float* __restrict__ dis,
                                                   const int* __restrict__ rowptr,
                                                   const int* __restrict__ csr_src,
                                                   const float* __restrict__ csr_val,
                                                   const float* __restrict__ bias,
                                                   float* __restrict__ out,
                                                   float* __restrict__ pool, int n) {
    __shared__ float lpool[128];
    int tid = threadIdx.x;
    if (tid < 128) lpool[tid] = 0.f;
    __syncthreads();

    int wave = tid >> 6;
    int lane = tid & 63;
    int node = blockIdx.x * 16 + wave;

    if (node < n) {
        float di = dis[node];
        const float2* hwp = (const float2*)hw;
        float2 self = hwp[(size_t)node * 64 + lane];
        float a0 = di * self.x;
        float a1 = di * self.y;
        int beg = rowptr[node], end = rowptr[node + 1];
        for (int j = beg; j < end; j++) {
            int   s = csr_src[j];
            float v = csr_val[j];
            float2 hv = hwp[(size_t)s * 64 + lane];
            a0 += v * hv.x;
            a1 += v * hv.y;
        }
        float r0 = fmaxf(di * a0 + bias[lane * 2 + 0], 0.f);
        float r1 = fmaxf(di * a1 + bias[lane * 2 + 1], 0.f);
        ((float2*)out)[(size_t)node * 64 + lane] = make_float2(r0, r1);
        atomicAdd(&lpool[lane * 2 + 0], r0);
        atomicAdd(&lpool[lane * 2 + 1], r1);
    }
    __syncthreads();
    if (tid < 128) atomicAdd(&pool[tid], lpool[tid]);
}

// ---------------- MLP head (single block) ----------------

__global__ __launch_bounds__(128) void mlp_kernel(const float* __restrict__ pool,
                                                  const float* __restrict__ fw1, const float* __restrict__ fb1,
                                                  const float* __restrict__ fw2, const float* __restrict__ fb2,
                                                  const float* __restrict__ fw3, const float* __restrict__ fb3,
                                                  float* __restrict__ out) {
    __shared__ float h0[384];
    __shared__ float h1[128];
    __shared__ float h2[64];
    int tid = threadIdx.x;   // 128
    for (int i = tid; i < 384; i += 128) h0[i] = pool[i];
    __syncthreads();
    {
        float s = fb1[tid];
        for (int k = 0; k < 384; k++) s += h0[k] * fw1[k * 128 + tid];
        h1[tid] = fmaxf(s, 0.f);
    }
    __syncthreads();
    if (tid < 64) {
        float s = fb2[tid];
        for (int k = 0; k < 128; k++) s += h1[k] * fw2[k * 64 + tid];
        h2[tid] = fmaxf(s, 0.f);
    }
    __syncthreads();
    if (tid < 10) {
        float s = fb3[tid];
        for (int k = 0; k < 64; k++) s += h2[k] * fw3[k * 10 + tid];
        out[tid] = s;
    }
}

// ---------------- launch ----------------

extern "C" void kernel_launch(void* const* d_in, const int* in_sizes, int n_in,
                              void* d_out, int out_size, void* d_ws, size_t ws_size,
                              hipStream_t stream) {
    const float* x   = (const float*)d_in[0];
    const int*   ei  = (const int*)d_in[1];
    const float* W1  = (const float*)d_in[2];
    const float* b1  = (const float*)d_in[3];
    const float* W2  = (const float*)d_in[4];
    const float* b2  = (const float*)d_in[5];
    const float* W3  = (const float*)d_in[6];
    const float* b3  = (const float*)d_in[7];
    const float* fw1 = (const float*)d_in[8];
    const float* fb1 = (const float*)d_in[9];
    const float* fw2 = (const float*)d_in[10];
    const float* fb2 = (const float*)d_in[11];
    const float* fw3 = (const float*)d_in[12];
    const float* fb3 = (const float*)d_in[13];
    float* out = (float*)d_out;

    const int n  = in_sizes[0] / FDIM;   // 50000
    const int ne = in_sizes[1] / 2;      // 600000
    const int* src = ei;
    const int* tgt = ei + ne;

    // workspace layout (all offsets 16B-aligned)
    char* ws = (char*)d_ws;
    size_t featBytes = (size_t)n * FDIM * sizeof(float);     // 25.6 MB
    float* hw   = (float*)ws;                 ws += featBytes;
    float* bufB = (float*)ws;                 ws += featBytes;   // x1 / x3
    float* bufC = (float*)ws;                 ws += featBytes;   // x2
    float* dis  = (float*)ws;                 ws += (size_t)n * 4;
    int* count  = (int*)ws;                   ws += (size_t)n * 4;
    int* rowptr = (int*)ws;                   ws += ((size_t)(n + 4) * 4 / 16) * 16;
    int* cursor = (int*)ws;                   ws += (size_t)n * 4;
    int* csr_src = (int*)ws;                  ws += (size_t)ne * 4;
    float* csr_val = (float*)ws;              ws += (size_t)ne * 4;
    float* pool = (float*)ws;                 ws += 384 * 4;

    // zero accumulators (ws is poisoned 0xAA before every call)
    hipMemsetAsync(count, 0, (size_t)n * 4, stream);
    hipMemsetAsync(pool, 0, 384 * 4, stream);

    // CSR build (once; reused by all 3 layers)
    hist_kernel<<<(ne + 255) / 256, 256, 0, stream>>>(tgt, count, ne);
    dis_kernel<<<(n + 255) / 256, 256, 0, stream>>>(count, dis, n);
    scan_kernel<<<1, 1024, 0, stream>>>(count, rowptr, cursor, n);
    fill_kernel<<<(ne + 255) / 256, 256, 0, stream>>>(src, tgt, dis, cursor, csr_src, csr_val, ne);

    int gemmGrid = (n + 127) / 128;
    int aggGrid  = (n + 15) / 16;

    // layer 1: x -> bufB
    gemm_kernel<<<gemmGrid, 256, 0, stream>>>(x, W1, hw, n);
    agg_kernel<<<aggGrid, 1024, 0, stream>>>(hw, dis, rowptr, csr_src, csr_val, b1, bufB, pool + 0, n);
    // layer 2: bufB -> bufC
    gemm_kernel<<<gemmGrid, 256, 0, stream>>>(bufB, W2, hw, n);
    agg_kernel<<<aggGrid, 1024, 0, stream>>>(hw, dis, rowptr, csr_src, csr_val, b2, bufC, pool + 128, n);
    // layer 3: bufC -> bufB (x1 no longer needed)
    gemm_kernel<<<gemmGrid, 256, 0, stream>>>(bufC, W3, hw, n);
    agg_kernel<<<aggGrid, 1024, 0, stream>>>(hw, dis, rowptr, csr_src, csr_val, b3, bufB, pool + 256, n);

    // head
    mlp_kernel<<<1, 128, 0, stream>>>(pool, fw1, fb1, fw2, fb2, fw3, fb3, out);
}

// Round 2
// 707.111 us; speedup vs baseline: 1.1399x; 1.1399x over previous
//
#include <hip/hip_runtime.h>

#define FDIM 128

// ---------------- helpers ----------------

__device__ __forceinline__ unsigned int cvt_bf16(float f) {
    unsigned int u = __float_as_uint(f);
    return (u + 0x7fffu + ((u >> 16) & 1u)) >> 16;   // RNE
}
__device__ __forceinline__ float bf16_lo(unsigned int w) { return __uint_as_float(w << 16); }
__device__ __forceinline__ float bf16_hi(unsigned int w) { return __uint_as_float(w & 0xffff0000u); }

// ---------------- CSR build ----------------

__global__ void hist_kernel(const int* __restrict__ tgt, int* __restrict__ count, int ne) {
    int e = blockIdx.x * blockDim.x + threadIdx.x;
    if (e < ne) atomicAdd(&count[tgt[e]], 1);
}

__global__ void dis_kernel(const int* __restrict__ count, float* __restrict__ dis, int n) {
    int i = blockIdx.x * blockDim.x + threadIdx.x;
    if (i < n) {
        float d = (float)(count[i] + 1);   // +1 self-loop
        dis[i] = rsqrtf(d);
    }
}

// single-block exclusive scan over n counts -> rowptr[0..n], cursor copy
__global__ void scan_kernel(const int* __restrict__ count, int* __restrict__ rowptr,
                            int* __restrict__ cursor, int n) {
    __shared__ int sums[1024];
    int tid = threadIdx.x;
    int chunk = (n + 1023) / 1024;
    int start = tid * chunk;
    int end   = min(start + chunk, n);
    int s = 0;
    for (int i = start; i < end; i++) s += count[i];
    sums[tid] = s;
    __syncthreads();
    for (int off = 1; off < 1024; off <<= 1) {
        int v = sums[tid];
        int u = (tid >= off) ? sums[tid - off] : 0;
        __syncthreads();
        sums[tid] = v + u;
        __syncthreads();
    }
    int run = (tid == 0) ? 0 : sums[tid - 1];
    for (int i = start; i < end; i++) {
        rowptr[i] = run;
        cursor[i] = run;
        run += count[i];
    }
    if (tid == 1023) rowptr[n] = run;
}

// csr entry: .x = src node, .y = float bits of dis[src]  (one dwordx2 load in agg)
__global__ void fill_kernel(const int* __restrict__ src, const int* __restrict__ tgt,
                            const float* __restrict__ dis,
                            int* __restrict__ cursor, int2* __restrict__ csr, int ne) {
    int e = blockIdx.x * blockDim.x + threadIdx.x;
    if (e < ne) {
        int t = tgt[e];
        int s = src[e];
        int slot = atomicAdd(&cursor[t], 1);
        csr[slot] = make_int2(s, __float_as_int(dis[s]));
    }
}

// ---------------- GEMM: Out[n][128] = A[n][128] @ W[128][128], bf16-packed out --------
// block 256 threads, tile 128x128, micro-tile 8x8, BK=32

__global__ __launch_bounds__(256) void gemm_kernel(const float* __restrict__ A,
                                                   const float* __restrict__ W,
                                                   unsigned int* __restrict__ Out, int n) {
    __shared__ float As[32][128];   // [k][m]
    __shared__ float Bs[32][128];   // [k][j]
    int tid = threadIdx.x;
    int tx = tid & 15;
    int ty = tid >> 4;
    int row0 = blockIdx.x * 128;
    float acc[8][8] = {};

    for (int k0 = 0; k0 < 128; k0 += 32) {
        {
            int r  = tid >> 1;
            int c4 = (tid & 1) * 4;
            int grow = row0 + r;
            const float4* ap = (const float4*)(A + (size_t)grow * FDIM + k0);
            #pragma unroll
            for (int i = 0; i < 4; i++) {
                float4 v = (grow < n) ? ap[c4 + i] : make_float4(0.f, 0.f, 0.f, 0.f);
                int kk = (c4 + i) * 4;
                As[kk + 0][r] = v.x;
                As[kk + 1][r] = v.y;
                As[kk + 2][r] = v.z;
                As[kk + 3][r] = v.w;
            }
            #pragma unroll
            for (int i = 0; i < 4; i++) {
                int f  = tid + i * 256;
                int kk = f >> 5;
                int j4 = f & 31;
                float4 v = ((const float4*)(W + (size_t)(k0 + kk) * FDIM))[j4];
                *((float4*)&Bs[kk][j4 * 4]) = v;
            }
        }
        __syncthreads();
        #pragma unroll
        for (int k = 0; k < 32; k++) {
            float a[8], b[8];
            *(float4*)&a[0] = *(const float4*)&As[k][ty * 8];
            *(float4*)&a[4] = *(const float4*)&As[k][ty * 8 + 4];
            *(float4*)&b[0] = *(const float4*)&Bs[k][tx * 8];
            *(float4*)&b[4] = *(const float4*)&Bs[k][tx * 8 + 4];
            #pragma unroll
            for (int m = 0; m < 8; m++)
                #pragma unroll
                for (int j = 0; j < 8; j++)
                    acc[m][j] += a[m] * b[j];
        }
        __syncthreads();
    }

    // epilogue: pack to bf16 pairs, 4 uints per row (cols tx*8..tx*8+7)
    #pragma unroll
    for (int m = 0; m < 8; m++) {
        int r = row0 + ty * 8 + m;
        if (r < n) {
            uint4 w;
            w.x = cvt_bf16(acc[m][0]) | (cvt_bf16(acc[m][1]) << 16);
            w.y = cvt_bf16(acc[m][2]) | (cvt_bf16(acc[m][3]) << 16);
            w.z = cvt_bf16(acc[m][4]) | (cvt_bf16(acc[m][5]) << 16);
            w.w = cvt_bf16(acc[m][6]) | (cvt_bf16(acc[m][7]) << 16);
            *((uint4*)(Out + (size_t)r * 64 + tx * 4)) = w;
        }
    }
}

// ---------------- Aggregation (pull, batched gathers) + bias + relu + pool -----------
// block 1024 = 16 waves, one wave per node; lane handles 2 bf16 features (1 uint)

__global__ __launch_bounds__(1024) void agg_kernel(const unsigned int* __restrict__ hw16,
                                                   const float* __restrict__ dis,
                                                   const int* __restrict__ rowptr,
                                                   const int2* __restrict__ csr,
                                                   const float* __restrict__ bias,
                                                   float* __restrict__ out,
                                                   float* __restrict__ pool, int n) {
    __shared__ float lpool[128];
    int tid = threadIdx.x;
    if (tid < 128) lpool[tid] = 0.f;
    __syncthreads();

    int wave = tid >> 6;
    int lane = tid & 63;
    int node = blockIdx.x * 16 + wave;

    if (node < n) {
        float di = dis[node];
        unsigned int su = hw16[(unsigned)node * 64u + lane];
        float a0 = di * bf16_lo(su);
        float a1 = di * bf16_hi(su);
        int beg = rowptr[node], end = rowptr[node + 1];
        for (int b = beg; b < end; b += 64) {
            int m = min(64, end - b);
            int sreg = 0; float vreg = 0.f;
            if (lane < m) {
                int2 e = csr[b + lane];
                sreg = e.x;
                vreg = __int_as_float(e.y);
            }
            for (int j = 0; j < m; j += 8) {
                unsigned int g[8]; float vv[8];
                #pragma unroll
                for (int q = 0; q < 8; q++) {
                    int s  = __shfl(sreg, j + q);
                    vv[q]  = __shfl(vreg, j + q);   // 0 for padded slots -> contributes 0
                    g[q]   = hw16[(unsigned)s * 64u + lane];
                }
                #pragma unroll
                for (int q = 0; q < 8; q++) {
                    a0 += vv[q] * bf16_lo(g[q]);
                    a1 += vv[q] * bf16_hi(g[q]);
                }
            }
        }
        float r0 = fmaxf(di * a0 + bias[lane * 2 + 0], 0.f);
        float r1 = fmaxf(di * a1 + bias[lane * 2 + 1], 0.f);
        ((float2*)out)[(unsigned)node * 64u + lane] = make_float2(r0, r1);
        atomicAdd(&lpool[lane * 2 + 0], r0);
        atomicAdd(&lpool[lane * 2 + 1], r1);
    }
    __syncthreads();
    if (tid < 128) atomicAdd(&pool[tid], lpool[tid]);
}

// ---------------- MLP head (single block) ----------------

__global__ __launch_bounds__(128) void mlp_kernel(const float* __restrict__ pool,
                                                  const float* __restrict__ fw1, const float* __restrict__ fb1,
                                                  const float* __restrict__ fw2, const float* __restrict__ fb2,
                                                  const float* __restrict__ fw3, const float* __restrict__ fb3,
                                                  float* __restrict__ out) {
    __shared__ float h0[384];
    __shared__ float h1[128];
    __shared__ float h2[64];
    int tid = threadIdx.x;
    for (int i = tid; i < 384; i += 128) h0[i] = pool[i];
    __syncthreads();
    {
        float s = fb1[tid];
        for (int k = 0; k < 384; k++) s += h0[k] * fw1[k * 128 + tid];
        h1[tid] = fmaxf(s, 0.f);
    }
    __syncthreads();
    if (tid < 64) {
        float s = fb2[tid];
        for (int k = 0; k < 128; k++) s += h1[k] * fw2[k * 64 + tid];
        h2[tid] = fmaxf(s, 0.f);
    }
    __syncthreads();
    if (tid < 10) {
        float s = fb3[tid];
        for (int k = 0; k < 64; k++) s += h2[k] * fw3[k * 10 + tid];
        out[tid] = s;
    }
}

// ---------------- launch ----------------

extern "C" void kernel_launch(void* const* d_in, const int* in_sizes, int n_in,
                              void* d_out, int out_size, void* d_ws, size_t ws_size,
                              hipStream_t stream) {
    const float* x   = (const float*)d_in[0];
    const int*   ei  = (const int*)d_in[1];
    const float* W1  = (const float*)d_in[2];
    const float* b1  = (const float*)d_in[3];
    const float* W2  = (const float*)d_in[4];
    const float* b2  = (const float*)d_in[5];
    const float* W3  = (const float*)d_in[6];
    const float* b3  = (const float*)d_in[7];
    const float* fw1 = (const float*)d_in[8];
    const float* fb1 = (const float*)d_in[9];
    const float* fw2 = (const float*)d_in[10];
    const float* fb2 = (const float*)d_in[11];
    const float* fw3 = (const float*)d_in[12];
    const float* fb3 = (const float*)d_in[13];
    float* out = (float*)d_out;

    const int n  = in_sizes[0] / FDIM;   // 50000
    const int ne = in_sizes[1] / 2;      // 600000
    const int* src = ei;
    const int* tgt = ei + ne;

    // workspace layout (all offsets 16B-aligned)
    char* ws = (char*)d_ws;
    size_t featBytes = (size_t)n * FDIM * sizeof(float);       // 25.6 MB
    unsigned int* hw = (unsigned int*)ws; ws += (size_t)n * 64 * sizeof(unsigned int); // bf16x2, 12.8 MB
    float* bufB = (float*)ws;             ws += featBytes;     // x1 / x3
    float* bufC = (float*)ws;             ws += featBytes;     // x2
    float* dis  = (float*)ws;             ws += (size_t)n * 4;
    int* count  = (int*)ws;               ws += (size_t)n * 4;
    int* rowptr = (int*)ws;               ws += ((size_t)(n + 4) * 4 / 16) * 16;
    int* cursor = (int*)ws;               ws += (size_t)n * 4;
    int2* csr   = (int2*)ws;              ws += (size_t)ne * 8;
    float* pool = (float*)ws;             ws += 384 * 4;

    hipMemsetAsync(count, 0, (size_t)n * 4, stream);
    hipMemsetAsync(pool, 0, 384 * 4, stream);

    hist_kernel<<<(ne + 255) / 256, 256, 0, stream>>>(tgt, count, ne);
    dis_kernel<<<(n + 255) / 256, 256, 0, stream>>>(count, dis, n);
    scan_kernel<<<1, 1024, 0, stream>>>(count, rowptr, cursor, n);
    fill_kernel<<<(ne + 255) / 256, 256, 0, stream>>>(src, tgt, dis, cursor, csr, ne);

    int gemmGrid = (n + 127) / 128;
    int aggGrid  = (n + 15) / 16;

    gemm_kernel<<<gemmGrid, 256, 0, stream>>>(x, W1, hw, n);
    agg_kernel<<<aggGrid, 1024, 0, stream>>>(hw, dis, rowptr, csr, b1, bufB, pool + 0, n);

    gemm_kernel<<<gemmGrid, 256, 0, stream>>>(bufB, W2, hw, n);
    agg_kernel<<<aggGrid, 1024, 0, stream>>>(hw, dis, rowptr, csr, b2, bufC, pool + 128, n);

    gemm_kernel<<<gemmGrid, 256, 0, stream>>>(bufC, W3, hw, n);
    agg_kernel<<<aggGrid, 1024, 0, stream>>>(hw, dis, rowptr, csr, b3, bufB, pool + 256, n);

    mlp_kernel<<<1, 128, 0, stream>>>(pool, fw1, fb1, fw2, fb2, fw3, fb3, out);
}